// Round 7
// baseline (620.135 us; speedup 1.0000x reference)
//
#include <hip/hip_runtime.h>
#include <hip/hip_fp16.h>
#include <hip/hip_cooperative_groups.h>
#include <math.h>

namespace cg = cooperative_groups;

// GCN 2-layer (DGL GraphConv norm='both'), ONE cooperative kernel.
// Round-6 structure (two-level MSD counting sort on dst+src, zero global
// atomics, fp16 featw1 with W1 in 64 named VGPRs, pre-scaled featp, wave/node
// agg1, 16-lane/node agg2) fused into a single hipLaunchCooperativeKernel
// with grid.sync() between phases. Rationale: totals minus measured kernel
// times stayed ~140us across rounds 0/3/6 regardless of sort-work removed,
// implying ~8-10us per launch boundary x 8 launches. All phases are
// grid-stride -> correct for ANY grid size; grid = CUs x occupancy (queried).
//   P1: per-block LDS hists of dst>>8 / src>>8 -> dhist[bin*T+b | M+...]
//       co-scheduled with featw1 chunks (64 rows/chunk via LDS ftile).
//   P2: per-chunk sums of dhist[2M] -> bsum[NSB]
//   P3: each chunk re-scans bsum locally (75 elems) + scans its 2048 elems
//       -> dhist holds flat exclusive prefixes (src section offset +E)
//   P4: partition: single pass, both scatters from precomputed bases
//   P5: finalize: dst bins -> in_deg/row_start/csr_src; src bins -> out_deg
//       + featp *= rsqrt(out_deg)
//   P6: agg1 (wave/node, relu+b1+.W2 -> s_buf)   P7: agg2 (sigmoid -> out)
// Requires N <= 65536 (src packed into 17 bits, NB <= 256). N=50000 here.

#define BS 256
#define EPB 2048    // edges per hist/partition chunk (8 iters of 256)
#define SCB 2048    // elements per scan chunk (256 thr x 8)

__global__ __launch_bounds__(256, 4)
void gcn_mega_kernel(const int* __restrict__ src, const int* __restrict__ dst,
                     const float* __restrict__ feat, const float* __restrict__ W1,
                     const float* __restrict__ b1, const float* __restrict__ W2,
                     const float* __restrict__ b2,
                     int* __restrict__ dhist, int* __restrict__ bsum,
                     int* __restrict__ in_deg, int* __restrict__ row_start,
                     int* __restrict__ out_deg, int* __restrict__ packed,
                     unsigned char* __restrict__ srcPartB, int* __restrict__ csr_src,
                     __half* __restrict__ featp, float* __restrict__ s_buf,
                     float* __restrict__ out,
                     int E, int N, int NB, int T, int M, int NSB, int NF, int NA1, int NA2)
{
    cg::grid_group grid = cg::this_grid();
    __shared__ float4 ftile[64 * 16];   // 16KB feat tile (featw1 only)
    __shared__ int shA[256];
    __shared__ int shB[256];
    const int tid = threadIdx.x;
    const int nblk = gridDim.x;
    const int M2 = 2 * M;

    // ---------------- P1: hists + featw1 ----------------
    for (int vb = blockIdx.x; vb < T + NF; vb += nblk) {
        if (vb < T) {
            shA[tid] = 0; shB[tid] = 0;
            __syncthreads();
            int base = vb * EPB;
            #pragma unroll
            for (int it = 0; it < EPB / BS; it++) {
                int e = base + it * BS + tid;
                if (e < E) {
                    atomicAdd(&shA[dst[e] >> 8], 1);
                    atomicAdd(&shB[src[e] >> 8], 1);
                }
            }
            __syncthreads();
            if (tid < NB) {
                dhist[tid * T + vb] = shA[tid];
                dhist[M + tid * T + vb] = shB[tid];
            }
            __syncthreads();
        } else {
            int lane = tid & 63, wave = tid >> 6;
            // W1 column for this lane: 64 named scalars (static -> registers)
            #define WD(i) float wv##i = W1[(i) * 64 + lane];
            WD(0)  WD(1)  WD(2)  WD(3)  WD(4)  WD(5)  WD(6)  WD(7)
            WD(8)  WD(9)  WD(10) WD(11) WD(12) WD(13) WD(14) WD(15)
            WD(16) WD(17) WD(18) WD(19) WD(20) WD(21) WD(22) WD(23)
            WD(24) WD(25) WD(26) WD(27) WD(28) WD(29) WD(30) WD(31)
            WD(32) WD(33) WD(34) WD(35) WD(36) WD(37) WD(38) WD(39)
            WD(40) WD(41) WD(42) WD(43) WD(44) WD(45) WD(46) WD(47)
            WD(48) WD(49) WD(50) WD(51) WD(52) WD(53) WD(54) WD(55)
            WD(56) WD(57) WD(58) WD(59) WD(60) WD(61) WD(62) WD(63)
            #undef WD
            int rBase = (vb - T) * 64;
            const float4* feat4 = (const float4*)feat;
            int maxF4 = N * 16 - 1;
            #pragma unroll
            for (int it = 0; it < 4; it++) {
                int idx = it * BS + tid;
                ftile[idx] = feat4[min(rBase * 16 + idx, maxF4)];
            }
            __syncthreads();
            #pragma unroll 1
            for (int rr = 0; rr < 16; rr++) {
                int r = wave * 16 + rr;
                const float4* ft = &ftile[r * 16];
                float a0 = 0.0f, a1 = 0.0f, a2 = 0.0f, a3 = 0.0f;
                #define RK(k4, wA, wB, wC, wD_) { float4 f = ft[k4]; \
                    a0 = fmaf(f.x, wA, a0); a1 = fmaf(f.y, wB, a1); \
                    a2 = fmaf(f.z, wC, a2); a3 = fmaf(f.w, wD_, a3); }
                RK(0,  wv0,  wv1,  wv2,  wv3)  RK(1,  wv4,  wv5,  wv6,  wv7)
                RK(2,  wv8,  wv9,  wv10, wv11) RK(3,  wv12, wv13, wv14, wv15)
                RK(4,  wv16, wv17, wv18, wv19) RK(5,  wv20, wv21, wv22, wv23)
                RK(6,  wv24, wv25, wv26, wv27) RK(7,  wv28, wv29, wv30, wv31)
                RK(8,  wv32, wv33, wv34, wv35) RK(9,  wv36, wv37, wv38, wv39)
                RK(10, wv40, wv41, wv42, wv43) RK(11, wv44, wv45, wv46, wv47)
                RK(12, wv48, wv49, wv50, wv51) RK(13, wv52, wv53, wv54, wv55)
                RK(14, wv56, wv57, wv58, wv59) RK(15, wv60, wv61, wv62, wv63)
                #undef RK
                int rowg = rBase + r;
                if (rowg < N)
                    featp[(size_t)rowg * 64 + lane] = __float2half((a0 + a1) + (a2 + a3));
            }
            __syncthreads();   // ftile reused next iteration
        }
    }
    grid.sync();

    // ---------------- P2: chunk sums -> bsum ----------------
    for (int vb = blockIdx.x; vb < NSB; vb += nblk) {
        int base = vb * SCB + tid * 8;
        int sum = 0;
        #pragma unroll
        for (int i = 0; i < 8; i++) { int k = base + i; if (k < M2) sum += dhist[k]; }
        shA[tid] = sum; __syncthreads();
        for (int off = 1; off < 256; off <<= 1) {
            int u = (tid >= off) ? shA[tid - off] : 0; __syncthreads();
            shA[tid] += u; __syncthreads();
        }
        if (tid == 255) bsum[vb] = shA[255];
        __syncthreads();
    }
    grid.sync();

    // ---------------- P3: full exclusive scan of dhist in place ----------------
    for (int vb = blockIdx.x; vb < NSB; vb += nblk) {
        int v0 = (tid < NSB) ? bsum[tid] : 0;       // local re-scan of block sums
        shA[tid] = v0; __syncthreads();
        for (int off = 1; off < 256; off <<= 1) {
            int u = (tid >= off) ? shA[tid - off] : 0; __syncthreads();
            shA[tid] += u; __syncthreads();
        }
        int blkBase = (vb > 0) ? shA[vb - 1] : 0;   // exclusive prefix of chunk vb
        int base = vb * SCB + tid * 8;
        int v[8]; int sum = 0;
        #pragma unroll
        for (int i = 0; i < 8; i++) { int k = base + i; v[i] = (k < M2) ? dhist[k] : 0; sum += v[i]; }
        shB[tid] = sum; __syncthreads();
        for (int off = 1; off < 256; off <<= 1) {
            int u = (tid >= off) ? shB[tid - off] : 0; __syncthreads();
            shB[tid] += u; __syncthreads();
        }
        int run = blkBase + shB[tid] - sum;
        #pragma unroll
        for (int i = 0; i < 8; i++) { int k = base + i; if (k < M2) dhist[k] = run; run += v[i]; }
        __syncthreads();
    }
    grid.sync();

    // ---------------- P4: partition (both scatters, one pass) ----------------
    for (int vb = blockIdx.x; vb < T; vb += nblk) {
        shA[tid] = (tid < NB) ? dhist[tid * T + vb] : 0;
        shB[tid] = (tid < NB) ? (dhist[M + tid * T + vb] - E) : 0;
        __syncthreads();
        int base = vb * EPB;
        #pragma unroll
        for (int it = 0; it < EPB / BS; it++) {
            int e = base + it * BS + tid;
            if (e < E) {
                int d = dst[e], s2 = src[e];
                int pos = atomicAdd(&shA[d >> 8], 1);
                packed[pos] = s2 | ((d & 255) << 17);
                int pos2 = atomicAdd(&shB[s2 >> 8], 1);
                srcPartB[pos2] = (unsigned char)(s2 & 255);
            }
        }
        __syncthreads();
    }
    grid.sync();

    // ---------------- P5: finalize ----------------
    for (int vb = blockIdx.x; vb < 2 * NB; vb += nblk) {
        if (vb < NB) {
            int b = vb;
            int lo = dhist[b * T];
            int hi = (b + 1 < NB) ? dhist[(b + 1) * T] : E;
            shA[tid] = 0; __syncthreads();
            for (int i = lo + tid; i < hi; i += BS)
                atomicAdd(&shA[(packed[i] >> 17) & 255], 1);
            __syncthreads();
            int v = shA[tid];
            shB[tid] = v; __syncthreads();
            for (int off = 1; off < 256; off <<= 1) {
                int u = (tid >= off) ? shB[tid - off] : 0; __syncthreads();
                shB[tid] += u; __syncthreads();
            }
            int ex = shB[tid] - v;
            int n = b * 256 + tid;
            if (n < N) { in_deg[n] = v; row_start[n] = lo + ex; }
            shB[tid] = lo + ex;
            __syncthreads();
            for (int i = lo + tid; i < hi; i += BS) {
                int pv = packed[i];
                int pos = atomicAdd(&shB[(pv >> 17) & 255], 1);
                csr_src[pos] = pv & 0x1FFFF;
            }
            __syncthreads();
        } else {
            int sb = vb - NB;
            int lo = dhist[M + sb * T] - E;
            int hi = ((sb + 1 < NB) ? dhist[M + (sb + 1) * T] : 2 * E) - E;
            shA[tid] = 0; __syncthreads();
            for (int i = lo + tid; i < hi; i += BS)
                atomicAdd(&shA[srcPartB[i]], 1);
            __syncthreads();
            int n = sb * 256 + tid;
            int od = shA[tid];
            if (n < N) out_deg[n] = od;
            float* snorm = (float*)shB;
            snorm[tid] = rsqrtf(fmaxf((float)od, 1.0f));
            __syncthreads();
            int nodes = min(256, N - sb * 256);
            uint4* fp = (uint4*)(featp + (size_t)sb * 256 * 64);
            int total = nodes * 8;
            for (int i = tid; i < total; i += BS) {
                float s = snorm[i >> 3];
                uint4 u = fp[i];
                __half2* hh = (__half2*)&u;
                #pragma unroll
                for (int c = 0; c < 4; c++) {
                    float2 p = __half22float2(hh[c]);
                    p.x *= s; p.y *= s;
                    hh[c] = __float22half2_rn(p);
                }
                fp[i] = u;
            }
            __syncthreads();
        }
    }
    grid.sync();

    // ---------------- P6: agg1 (one wave per node) ----------------
    for (int vb = blockIdx.x; vb < NA1; vb += nblk) {
        int n = vb * 4 + (tid >> 6);
        if (n < N) {
            int lane = tid & 63;
            int g = lane >> 3;
            int l = lane & 7;
            int start = row_start[n];
            int deg = in_deg[n];
            float acc[8] = {0, 0, 0, 0, 0, 0, 0, 0};
            const uint4* fp4 = (const uint4*)featp;
            for (int j = 0; j < deg; j += 16) {
                int e0 = j + g;
                int e1 = j + 8 + g;
                bool p0 = e0 < deg;
                bool p1 = e1 < deg;
                int sn0 = p0 ? csr_src[start + e0] : 0;
                int sn1 = p1 ? csr_src[start + e1] : 0;
                uint4 q0 = {0, 0, 0, 0}, q1 = {0, 0, 0, 0};
                if (p0) q0 = fp4[(size_t)sn0 * 8 + l];
                if (p1) q1 = fp4[(size_t)sn1 * 8 + l];
                const __half2* h0 = (const __half2*)&q0;
                const __half2* h1 = (const __half2*)&q1;
                #pragma unroll
                for (int c = 0; c < 4; c++) {
                    float2 f0 = __half22float2(h0[c]);
                    float2 f1 = __half22float2(h1[c]);
                    acc[2 * c]     += f0.x + f1.x;
                    acc[2 * c + 1] += f0.y + f1.y;
                }
            }
            #pragma unroll
            for (int off = 8; off < 64; off <<= 1) {
                #pragma unroll
                for (int c = 0; c < 8; c++)
                    acc[c] += __shfl_xor(acc[c], off, 64);
            }
            float inn = rsqrtf(fmaxf((float)deg, 1.0f));
            float v = 0.0f;
            #pragma unroll
            for (int c = 0; c < 8; c++) {
                float h = fmaxf(inn * acc[c] + b1[l * 8 + c], 0.0f);
                v += h * W2[l * 8 + c];
            }
            #pragma unroll
            for (int off = 1; off < 8; off <<= 1)
                v += __shfl_xor(v, off, 64);
            if (lane == 0)
                s_buf[n] = rsqrtf(fmaxf((float)out_deg[n], 1.0f)) * v;
        }
    }
    grid.sync();

    // ---------------- P7: agg2 (16 lanes per node) ----------------
    for (int vb = blockIdx.x; vb < NA2; vb += nblk) {
        int n = vb * 16 + (tid >> 4);
        if (n < N) {
            int sub = tid & 15;
            int start = row_start[n];
            int deg = in_deg[n];
            float a = 0.0f;
            for (int j = sub; j < deg; j += 32) {
                int j1 = j + 16;
                int i0 = csr_src[start + j];
                int i1 = (j1 < deg) ? csr_src[start + j1] : 0;
                float v0 = s_buf[i0];
                float v1 = (j1 < deg) ? s_buf[i1] : 0.0f;
                a += v0 + v1;
            }
            #pragma unroll
            for (int off = 1; off < 16; off <<= 1)
                a += __shfl_xor(a, off, 64);
            if (sub == 0) {
                float x = rsqrtf(fmaxf((float)deg, 1.0f)) * a + b2[0];
                out[n] = 1.0f / (1.0f + expf(-x));
            }
        }
    }
}

extern "C" void kernel_launch(void* const* d_in, const int* in_sizes, int n_in,
                              void* d_out, int out_size, void* d_ws, size_t ws_size,
                              hipStream_t stream) {
    const int* src = (const int*)d_in[5];
    const int* dst = (const int*)d_in[6];
    const float* feat = (const float*)d_in[0];
    const float* W1   = (const float*)d_in[1];
    const float* b1   = (const float*)d_in[2];
    const float* W2   = (const float*)d_in[3];
    const float* b2   = (const float*)d_in[4];
    float* out = (float*)d_out;

    int N  = in_sizes[0] / 64;       // 50000
    int E  = in_sizes[5];            // 800000
    int NB = (N + 255) >> 8;         // 196 bins of 256 nodes
    int T  = (E + EPB - 1) / EPB;    // 391 hist/partition chunks
    int M  = NB * T;                 // per-side flat (bin, chunk) counts
    int M2 = 2 * M;
    int NSB = (M2 + SCB - 1) / SCB;  // 75 scan chunks
    int NF  = (N + 63) / 64;         // 782 featw1 chunks
    int NA1 = (N + 3) / 4;           // 12500 agg1 chunks (4 nodes each)
    int NA2 = (N + 15) / 16;         // 3125 agg2 chunks (16 nodes each)

    // workspace: int region | srcPart bytes | fp16 featp (16B-aligned) | float s_buf
    int* wsi = (int*)d_ws;
    int* bsum        = wsi;                          // NSB
    int* in_deg      = bsum + NSB;                   // N
    int* row_start   = in_deg + N;                   // N
    int* out_deg     = row_start + N;                // N (fully written in P5)
    int* dhist       = out_deg + N;                  // 2*M (fully overwritten)
    int* packed      = dhist + M2;                   // E
    int* csr_src     = packed + E;                   // E
    unsigned char* srcPartB = (unsigned char*)(csr_src + E);      // E bytes
    size_t int_bytes = ((size_t)NSB + 3 * (size_t)N + (size_t)M2 + 2 * (size_t)E) * sizeof(int)
                     + (size_t)E;
    size_t half_off  = (int_bytes + 15) & ~(size_t)15;
    __half* featp = (__half*)((char*)d_ws + half_off);            // 64N fp16
    float* s_buf  = (float*)((char*)d_ws + half_off + (size_t)64 * N * sizeof(__half));

    // grid = CUs x occupancy (queried once; grid-stride phases are correct
    // for any grid size, so this can only under-fill, never deadlock)
    static int gridBlocks = 0;
    if (gridBlocks == 0) {
        int mb = 0;
        hipOccupancyMaxActiveBlocksPerMultiprocessor(&mb, gcn_mega_kernel, BS, 0);
        if (mb < 1) mb = 1;
        int dev = 0;
        hipGetDevice(&dev);
        hipDeviceProp_t prop;
        int cus = 256;
        if (hipGetDeviceProperties(&prop, dev) == hipSuccess && prop.multiProcessorCount > 0)
            cus = prop.multiProcessorCount;
        gridBlocks = cus * mb;
        if (gridBlocks > 2048) gridBlocks = 2048;
    }

    void* args[] = { (void*)&src, (void*)&dst, (void*)&feat, (void*)&W1,
                     (void*)&b1, (void*)&W2, (void*)&b2,
                     (void*)&dhist, (void*)&bsum, (void*)&in_deg, (void*)&row_start,
                     (void*)&out_deg, (void*)&packed, (void*)&srcPartB, (void*)&csr_src,
                     (void*)&featp, (void*)&s_buf, (void*)&out,
                     (void*)&E, (void*)&N, (void*)&NB, (void*)&T, (void*)&M,
                     (void*)&NSB, (void*)&NF, (void*)&NA1, (void*)&NA2 };
    hipLaunchCooperativeKernel(gcn_mega_kernel, dim3(gridBlocks), dim3(BS),
                               args, 0, stream);
}